// Round 5
// baseline (698.816 us; speedup 1.0000x reference)
//
#include <hip/hip_runtime.h>
#include <hip/hip_cooperative_groups.h>
#include <hip/hip_fp16.h>
#include <math.h>

namespace cg = cooperative_groups;

// B=4096, D=768, K=60. Output: scalar fp32 mean CE loss, label 0.
// loss_b = logsumexp(logits_b) - logits_b[0].
//
// Round 0-4 ledger: totals 103.4/104.7/134.8/106.5 across 4 different
// multi-kernel structures. Accounting (R3: measured 62us gather + 45us
// re-poison fill + ~20us gaps = 134.8) shows the timed window is
// ~45us fill (fixed) + ~45-50us kernels + 10-15us DISPATCH GAPS.
// This round: ONE cooperative kernel (guide-blessed), grid.sync between
// phases. Structural wins vs R4:
//  * wave = row: user row loaded 1x (was 8x), negidx 1x, and the whole
//    LSE runs in-wave (each lane ends with 8 of the 64 logits) -> no
//    logits ws round-trip, no lse kernel, no memset/atomic.
//  * explicit double-buffered gather (2 x 48 VGPR of load data in
//    flight) -- R3's VGPR_Count=36 proved loads were issue-serialized.
//  * 1 dispatch total: no gaps.

#define NB 4096
#define ND 768
#define NK 60
#define ND4  (ND / 4)          // 192 float4 per fp32 row
#define NDU  (ND / 2)          // 384 uints per fp16 row
#define NLOGITS (NK + 1)       // 61
#define NPAD 64

#define NBLK 2048              // single-wave blocks (cooperative grid)
#define NTHR 64

#define WS_ITEMS_OFF 0
#define WS_PART_OFF  ((size_t)NB * ND * 2)              // 6.29 MB
#define WS_NEED      (WS_PART_OFF + (size_t)NBLK * 4)

typedef _Float16 h2 __attribute__((ext_vector_type(2)));
typedef float    f2 __attribute__((ext_vector_type(2)));
typedef float    f4v __attribute__((ext_vector_type(4)));

__device__ __forceinline__ float dot2_acc(unsigned int u, unsigned int v, float c) {
#if __has_builtin(__builtin_amdgcn_fdot2)
    return __builtin_amdgcn_fdot2(__builtin_bit_cast(h2, u),
                                  __builtin_bit_cast(h2, v), c, false);
#else
    f2 a = __builtin_convertvector(__builtin_bit_cast(h2, u), f2);
    f2 b = __builtin_convertvector(__builtin_bit_cast(h2, v), f2);
    return c + a.x * b.x + a.y * b.y;
#endif
}

__device__ __forceinline__ unsigned int pack_h2(float x, float y) {
    h2 h = { (_Float16)x, (_Float16)y };
    return __builtin_bit_cast(unsigned int, h);
}

// Butterfly fold: 8 per-lane partials -> every lane holds the full 64-lane
// sum of logit (lane & 7).  (Verified: absmax 0 in rounds 0/2/3/4.)
__device__ __forceinline__ float fold8(const float acc[8], int lane) {
    const int bit0 = lane & 1;
    float n[4];
    #pragma unroll
    for (int j = 0; j < 4; ++j) {
        float mine  = bit0 ? acc[2*j+1] : acc[2*j];
        float other = bit0 ? acc[2*j]   : acc[2*j+1];
        n[j] = mine + __shfl_xor(other, 1, 64);
    }
    const int bit1 = (lane >> 1) & 1;
    float s[2];
    #pragma unroll
    for (int j = 0; j < 2; ++j) {
        float mine  = bit1 ? n[2*j+1] : n[2*j];
        float other = bit1 ? n[2*j]   : n[2*j+1];
        s[j] = mine + __shfl_xor(other, 2, 64);
    }
    const int bit2 = (lane >> 2) & 1;
    float mine  = bit2 ? s[1] : s[0];
    float other = bit2 ? s[0] : s[1];
    float r = mine + __shfl_xor(other, 4, 64);
    r += __shfl_xor(r, 8, 64);
    r += __shfl_xor(r, 16, 64);
    r += __shfl_xor(r, 32, 64);
    return r;
}

// ---- the whole problem in one cooperative kernel ----
__global__ __launch_bounds__(NTHR, 4) void u2i_all(
    const float* __restrict__ user,
    const f4v*  __restrict__ items,
    const int*  __restrict__ negidx,
    float* __restrict__ out,
    unsigned int* __restrict__ itemsh,
    float* __restrict__ partials)
{
    cg::grid_group grid = cg::this_grid();
    const int lane = threadIdx.x;      // single-wave block: tid == lane
    const int bid  = blockIdx.x;
    const int nblk = gridDim.x;

    // ---- phase 1: items fp32 -> fp16 (grid-stride) ----
    {
        const int stride = nblk * NTHR;
        for (int i = bid * NTHR + lane; i < NB * ND4; i += stride) {
            f4v v = __builtin_nontemporal_load(items + i);
            uint2 rv;
            rv.x = pack_h2(v.x, v.y);
            rv.y = pack_h2(v.z, v.w);
            ((uint2*)itemsh)[i] = rv;
        }
    }
    __threadfence();
    grid.sync();

    // ---- phase 2: one wave per row; double-buffered gather; in-wave LSE ----
    float wloss = 0.0f;

    for (int b = bid; b < NB; b += nblk) {
        // user row fp32 -> packed halves (once per row now)
        const float4* ur4 = (const float4*)(user + (size_t)b * ND);
        float4 uf0 = ur4[2 * lane];
        float4 uf1 = ur4[2 * lane + 1];
        float4 uf2 = ur4[128 + lane];
        uint4 ua;
        ua.x = pack_h2(uf0.x, uf0.y);
        ua.y = pack_h2(uf0.z, uf0.w);
        ua.z = pack_h2(uf1.x, uf1.y);
        ua.w = pack_h2(uf1.z, uf1.w);
        uint2 ub;
        ub.x = pack_h2(uf2.x, uf2.y);
        ub.y = pack_h2(uf2.z, uf2.w);

        const int* nrow = negidx + (size_t)b * NK;

        uint4 vaA[8], vaB[8];
        uint2 vbA[8], vbB[8];
        float rs[8];

        auto ldgather = [&](int s, uint4* va, uint2* vb) {
            #pragma unroll
            for (int i = 0; i < 8; ++i) {
                int k = s * 8 + i;
                int row = (k == 0 || k > NK) ? b : nrow[k - 1];
                const unsigned int* ir = itemsh + (size_t)row * NDU;
                va[i] = ((const uint4*)ir)[lane];
                vb[i] = ((const uint2*)(ir + 256))[lane];
            }
        };
        auto compute = [&](const uint4* va, const uint2* vb) -> float {
            float acc[8];
            #pragma unroll
            for (int i = 0; i < 8; ++i) {
                float a = 0.0f;
                a = dot2_acc(ua.x, va[i].x, a);
                a = dot2_acc(ua.y, va[i].y, a);
                a = dot2_acc(ua.z, va[i].z, a);
                a = dot2_acc(ua.w, va[i].w, a);
                a = dot2_acc(ub.x, vb[i].x, a);
                a = dot2_acc(ub.y, vb[i].y, a);
                acc[i] = a;
            }
            return fold8(acc, lane);
        };

        // software pipeline: slot s+1's 16 loads in flight under slot s's
        // dots + fold (fold is a ~300-cycle shuffle chain -- free overlap).
        ldgather(0, vaA, vbA);
        #pragma unroll
        for (int s = 0; s < 8; s += 2) {
            if (s + 1 < 8) ldgather(s + 1, vaB, vbB);
            rs[s] = compute(vaA, vbA);
            if (s + 2 < 8) ldgather(s + 2, vaA, vbA);
            if (s + 1 < 8) rs[s + 1] = compute(vaB, vbB);
        }

        // in-wave LSE: lane r=lane&7 holds logits {r, 8+r, ..., 56+r};
        // the 8-lane group covers all 64 slots (replicated x8 across wave).
        // valid logits 0..60: slots s<7 all valid; s=7 valid iff r<=4.
        const int r = lane & 7;
        float m = rs[0];
        #pragma unroll
        for (int s = 1; s < 7; ++s) m = fmaxf(m, rs[s]);
        m = (r <= 4) ? fmaxf(m, rs[7]) : m;
        m = fmaxf(m, __shfl_xor(m, 1, 64));
        m = fmaxf(m, __shfl_xor(m, 2, 64));
        m = fmaxf(m, __shfl_xor(m, 4, 64));
        float e = 0.0f;
        #pragma unroll
        for (int s = 0; s < 7; ++s) e += __expf(rs[s] - m);
        e += (r <= 4) ? __expf(rs[7] - m) : 0.0f;
        e += __shfl_xor(e, 1, 64);
        e += __shfl_xor(e, 2, 64);
        e += __shfl_xor(e, 4, 64);
        float p0 = __shfl(rs[0], 0, 64);   // lane 0 holds logit 0
        wloss += m + __logf(e) - p0;
    }

    if (lane == 0) partials[bid] = wloss;
    __threadfence();
    grid.sync();

    // ---- phase 3: block 0 reduces partials -> mean ----
    if (bid == 0) {
        float s = 0.0f;
        for (int j = lane; j < nblk; j += NTHR) s += partials[j];
        #pragma unroll
        for (int off = 32; off > 0; off >>= 1)
            s += __shfl_down(s, off, 64);
        if (lane == 0) out[0] = s * (1.0f / (float)NB);
    }
}

// ---- fallback (fp32 single-kernel path) if ws too small ----
__global__ __launch_bounds__(256) void u2i_loss_f32(
    const float* __restrict__ user,
    const float* __restrict__ items,
    const int* __restrict__ negidx,
    float* __restrict__ out)
{
    const int b    = blockIdx.x;
    const int tid  = threadIdx.x;
    const int wave = tid >> 6;
    const int lane = tid & 63;

    __shared__ int   rows_s[NPAD];
    __shared__ float logits[NPAD];

    if (tid < NPAD) {
        const int* nrow = negidx + (size_t)b * NK;
        rows_s[tid] = (tid == 0 || tid > NK) ? b : nrow[tid - 1];
    }
    const float4* u4 = (const float4*)user + (size_t)b * ND4;
    float4 u0 = u4[lane];
    float4 u1 = u4[64 + lane];
    float4 u2 = u4[128 + lane];
    __syncthreads();

    const float4* it4 = (const float4*)items;
    #pragma unroll
    for (int j = 0; j < 4; ++j) {
        int ks[4];
        const float4* p[4];
        #pragma unroll
        for (int i = 0; i < 4; ++i) {
            ks[i] = wave + j * 16 + i * 4;
            p[i]  = it4 + (size_t)rows_s[ks[i]] * ND4;
        }
        float4 v0[4], v1[4], v2[4];
        #pragma unroll
        for (int i = 0; i < 4; ++i) {
            v0[i] = p[i][lane];
            v1[i] = p[i][64 + lane];
            v2[i] = p[i][128 + lane];
        }
        float acc[4];
        #pragma unroll
        for (int i = 0; i < 4; ++i) {
            float a;
            a  = u0.x * v0[i].x + u0.y * v0[i].y + u0.z * v0[i].z + u0.w * v0[i].w;
            a += u1.x * v1[i].x + u1.y * v1[i].y + u1.z * v1[i].z + u1.w * v1[i].w;
            a += u2.x * v2[i].x + u2.y * v2[i].y + u2.z * v2[i].z + u2.w * v2[i].w;
            acc[i] = a;
        }
        #pragma unroll
        for (int off = 32; off > 0; off >>= 1) {
            #pragma unroll
            for (int i = 0; i < 4; ++i)
                acc[i] += __shfl_down(acc[i], off, 64);
        }
        if (lane == 0) {
            #pragma unroll
            for (int i = 0; i < 4; ++i)
                logits[ks[i]] = acc[i];
        }
    }
    __syncthreads();

    if (tid < 64) {
        float v = (tid < NLOGITS) ? logits[tid] : -INFINITY;
        float m = v;
        #pragma unroll
        for (int off = 32; off > 0; off >>= 1)
            m = fmaxf(m, __shfl_down(m, off, 64));
        m = __shfl(m, 0, 64);
        float e = (tid < NLOGITS) ? __expf(v - m) : 0.0f;
        #pragma unroll
        for (int off = 32; off > 0; off >>= 1)
            e += __shfl_down(e, off, 64);
        if (tid == 0) {
            float loss = m + __logf(e) - logits[0];
            atomicAdd(out, loss * (1.0f / (float)NB));
        }
    }
}

extern "C" void kernel_launch(void* const* d_in, const int* in_sizes, int n_in,
                              void* d_out, int out_size, void* d_ws, size_t ws_size,
                              hipStream_t stream) {
    const float* user  = (const float*)d_in[0];   // (B, D) fp32
    const float* items = (const float*)d_in[1];   // (B, D) fp32
    const int*   negi  = (const int*)d_in[2];     // (B, K) int32
    float* out = (float*)d_out;                   // scalar fp32

    if (ws_size >= WS_NEED) {
        char* ws = (char*)d_ws;
        unsigned int* itemsh   = (unsigned int*)(ws + WS_ITEMS_OFF);
        float*        partials = (float*)(ws + WS_PART_OFF);

        const f4v* items4 = (const f4v*)items;
        void* args[] = { (void*)&user, (void*)&items4, (void*)&negi,
                         (void*)&out, (void*)&itemsh, (void*)&partials };
        // __launch_bounds__(64,4) caps VGPR at 128 -> 16 single-wave
        // blocks/CU resident -> capacity 4096 blocks >= 2048 launched.
        hipLaunchCooperativeKernel((const void*)u2i_all,
                                   dim3(NBLK), dim3(NTHR),
                                   args, 0, stream);
    } else {
        hipMemsetAsync(out, 0, sizeof(float), stream);
        u2i_loss_f32<<<NB, 256, 0, stream>>>(user, items, negi, out);
    }
}

// Round 6
// 113.289 us; speedup vs baseline: 6.1685x; 6.1685x over previous
//
#include <hip/hip_runtime.h>
#include <hip/hip_fp16.h>
#include <math.h>

// B=4096, D=768, K=60. Output: scalar fp32 mean CE loss, label 0.
// loss_b = logsumexp(logits_b) - logits_b[0].
//
// Ledger: R0 103.4 (reg-gather) / R2 104.7 (plane split: null) /
// R3 134.8 (atomic serialization, gather VGPR=36) / R4 106.5
// (sched_barrier: null) / R5 698.8 (coop, VGPR=64, VALUBusy 1%).
// Consistent finding: hipcc NEVER allocates the 48-96 VGPRs needed to
// keep a register gather batch in flight -> gather is issue-latency-bound
// at ~35us (402 MB logical at only ~11 TB/s).
//
// This round: bypass the register allocator with global_load_lds DMA.
// Each wave stages its 8 item rows (12 KB) into a PRIVATE LDS region
// (24 DMA issues, zero VGPR load data, deep vmcnt queue), one
// vmcnt(0), then ds_read_b128 + v_dot2. No cross-wave LDS sharing ->
// no barriers. 48 KB/block -> 3 blocks/CU -> ~144 KB in flight per CU
// during staging (vs ~2 KB before).
//
// Phases: memset(out); convert_items_f16; gather_dots_lds; lse_reduce.

#define NB 4096
#define ND 768
#define NK 60
#define ND4  (ND / 4)          // 192 float4 per fp32 row
#define NDU  (ND / 2)          // 384 uints per fp16 row
#define NLOGITS (NK + 1)       // 61
#define NPAD 64
#define ROWB 1536              // bytes per fp16 row

#define WS_LOGITS_OFF 0
#define WS_ITEMS_OFF  ((size_t)NB * NPAD * 4)                   // 1 MB
#define WS_NEED       (WS_ITEMS_OFF + (size_t)NB * ND * 2)      // +6.29 MB

typedef _Float16 h2 __attribute__((ext_vector_type(2)));
typedef float    f2 __attribute__((ext_vector_type(2)));
typedef float    f4v __attribute__((ext_vector_type(4)));

__device__ __forceinline__ float dot2_acc(unsigned int u, unsigned int v, float c) {
#if __has_builtin(__builtin_amdgcn_fdot2)
    return __builtin_amdgcn_fdot2(__builtin_bit_cast(h2, u),
                                  __builtin_bit_cast(h2, v), c, false);
#else
    f2 a = __builtin_convertvector(__builtin_bit_cast(h2, u), f2);
    f2 b = __builtin_convertvector(__builtin_bit_cast(h2, v), f2);
    return c + a.x * b.x + a.y * b.y;
#endif
}

__device__ __forceinline__ unsigned int pack_h2(float x, float y) {
    h2 h = { (_Float16)x, (_Float16)y };
    return __builtin_bit_cast(unsigned int, h);
}

// global->LDS DMA. Global src is PER-LANE; LDS dest is wave-uniform base,
// HW writes dest + lane*size (guide m03/m97/m104). size must be literal.
__device__ __forceinline__ void gld_lds16(const void* g, void* l) {
    __builtin_amdgcn_global_load_lds(
        (const __attribute__((address_space(1))) unsigned int*)g,
        (__attribute__((address_space(3))) unsigned int*)l, 16, 0, 0);
}
__device__ __forceinline__ void gld_lds4(const void* g, void* l) {
    __builtin_amdgcn_global_load_lds(
        (const __attribute__((address_space(1))) unsigned int*)g,
        (__attribute__((address_space(3))) unsigned int*)l, 4, 0, 0);
}

// Butterfly fold: 8 per-lane partials -> every lane holds the full 64-lane
// sum of logit (lane & 7).  (Verified: absmax 0 in rounds 0/2/3/4/5.)
__device__ __forceinline__ float fold8(const float acc[8], int lane) {
    const int bit0 = lane & 1;
    float n[4];
    #pragma unroll
    for (int j = 0; j < 4; ++j) {
        float mine  = bit0 ? acc[2*j+1] : acc[2*j];
        float other = bit0 ? acc[2*j]   : acc[2*j+1];
        n[j] = mine + __shfl_xor(other, 1, 64);
    }
    const int bit1 = (lane >> 1) & 1;
    float s[2];
    #pragma unroll
    for (int j = 0; j < 2; ++j) {
        float mine  = bit1 ? n[2*j+1] : n[2*j];
        float other = bit1 ? n[2*j]   : n[2*j+1];
        s[j] = mine + __shfl_xor(other, 2, 64);
    }
    const int bit2 = (lane >> 2) & 1;
    float mine  = bit2 ? s[1] : s[0];
    float other = bit2 ? s[0] : s[1];
    float r = mine + __shfl_xor(other, 4, 64);
    r += __shfl_xor(r, 8, 64);
    r += __shfl_xor(r, 16, 64);
    r += __shfl_xor(r, 32, 64);
    return r;
}

// ---- phase 1: items fp32 -> fp16 (packed uint2 = 4 halves) ----
__global__ __launch_bounds__(256) void convert_items_f16(
    const f4v* __restrict__ items, uint2* __restrict__ itemsh)
{
    int i = blockIdx.x * 256 + threadIdx.x;
    f4v v = __builtin_nontemporal_load(items + i);
    uint2 rv;
    rv.x = pack_h2(v.x, v.y);
    rv.y = pack_h2(v.z, v.w);
    itemsh[i] = rv;
}

// ---- phase 2: one wave per 8 logits; LDS-DMA staged gather ----
__global__ __launch_bounds__(256) void gather_dots_lds(
    const float* __restrict__ user,
    const unsigned int* __restrict__ itemsh,
    const int* __restrict__ negidx,
    float* __restrict__ logits)
{
    const int tid  = threadIdx.x;
    const int lane = tid & 63;
    const int wv   = tid >> 6;                      // wave in block (0..3)
    const int w    = blockIdx.x * 4 + wv;           // global wave id
    const int b    = w >> 3;                        // row
    const int slot = w & 7;                         // 8 logits per slot

    // [wave][row][96 uint4] = 1536 B per row, 12 KB per wave, 48 KB total.
    __shared__ uint4 stage[4][8][96];

    // user row loads first (independent vmem, completes under the DMAs)
    const float4* ur4 = (const float4*)(user + (size_t)b * ND);
    float4 uf0 = ur4[2 * lane];        // elements 8l..8l+3
    float4 uf1 = ur4[2 * lane + 1];    // elements 8l+4..8l+7
    float4 uf2 = ur4[128 + lane];      // elements 512+4l..512+4l+3

    // 8 row indices (wave-uniform -> scalar loads)
    const int* nrow = negidx + (size_t)b * NK;
    int rows[8];
    #pragma unroll
    for (int i = 0; i < 8; ++i) {
        int k = slot * 8 + i;
        rows[i] = (k == 0 || k > NK) ? b : nrow[k - 1];
    }

    // 24 DMA issues: zero VGPR load data, all in flight at once.
    #pragma unroll
    for (int i = 0; i < 8; ++i) {
        const unsigned char* rg =
            (const unsigned char*)(itemsh + (size_t)rows[i] * NDU);
        // bytes 0..1023   (lane*16)
        gld_lds16(rg + lane * 16,        &stage[wv][i][0]);
        // bytes 1024..1279 (lane*4)
        gld_lds4 (rg + 1024 + lane * 4,  &stage[wv][i][64]);
        // bytes 1280..1535 (lane*4)
        gld_lds4 (rg + 1280 + lane * 4,  &stage[wv][i][80]);
    }

    // pack user row while DMAs fly (compiler waits only on the uf* loads)
    uint4 ua;
    ua.x = pack_h2(uf0.x, uf0.y);
    ua.y = pack_h2(uf0.z, uf0.w);
    ua.z = pack_h2(uf1.x, uf1.y);
    ua.w = pack_h2(uf1.z, uf1.w);
    uint2 ub;
    ub.x = pack_h2(uf2.x, uf2.y);
    ub.y = pack_h2(uf2.z, uf2.w);

    // drain the DMA queue; fence so no ds_read floats above it
    asm volatile("s_waitcnt vmcnt(0)" ::: "memory");
    __builtin_amdgcn_sched_barrier(0);

    float acc[8];
    #pragma unroll
    for (int i = 0; i < 8; ++i) {
        uint4 va = stage[wv][i][lane];                       // bytes l*16
        const uint2* rb = (const uint2*)&stage[wv][i][64];   // bytes 1024+
        uint2 vb = rb[lane];
        float a = 0.0f;
        a = dot2_acc(ua.x, va.x, a);
        a = dot2_acc(ua.y, va.y, a);
        a = dot2_acc(ua.z, va.z, a);
        a = dot2_acc(ua.w, va.w, a);
        a = dot2_acc(ub.x, vb.x, a);
        a = dot2_acc(ub.y, vb.y, a);
        acc[i] = a;
    }

    float r = fold8(acc, lane);
    if (lane < 8)
        logits[(size_t)b * NPAD + slot * 8 + lane] = r;
}

// ---- phase 3: thread = row; per-block partial; 16 atomics total ----
__global__ __launch_bounds__(256) void lse_reduce(
    const float* __restrict__ logits, float* __restrict__ out)
{
    const int tid = threadIdx.x;
    const int b   = blockIdx.x * 256 + tid;

    const float4* lr = (const float4*)(logits + (size_t)b * NPAD);
    float4 v[16];
    #pragma unroll
    for (int j = 0; j < 16; ++j)
        v[j] = lr[j];

    // valid logits: elements 0..60  (v[15].x is element 60)
    float m = v[0].x;
    #pragma unroll
    for (int j = 0; j < 15; ++j)
        m = fmaxf(m, fmaxf(fmaxf(v[j].x, v[j].y), fmaxf(v[j].z, v[j].w)));
    m = fmaxf(m, v[15].x);

    float e = 0.0f;
    #pragma unroll
    for (int j = 0; j < 15; ++j)
        e += __expf(v[j].x - m) + __expf(v[j].y - m) +
             __expf(v[j].z - m) + __expf(v[j].w - m);
    e += __expf(v[15].x - m);

    float loss = m + __logf(e) - v[0].x;

    #pragma unroll
    for (int off = 32; off > 0; off >>= 1)
        loss += __shfl_down(loss, off, 64);

    __shared__ float ps[4];
    if ((tid & 63) == 0) ps[tid >> 6] = loss;
    __syncthreads();
    if (tid == 0)
        atomicAdd(out, (ps[0] + ps[1] + ps[2] + ps[3]) * (1.0f / (float)NB));
}

// ---- fallback (fp32 single-kernel path) if ws too small ----
__global__ __launch_bounds__(256) void u2i_loss_f32(
    const float* __restrict__ user,
    const float* __restrict__ items,
    const int* __restrict__ negidx,
    float* __restrict__ out)
{
    const int b    = blockIdx.x;
    const int tid  = threadIdx.x;
    const int wave = tid >> 6;
    const int lane = tid & 63;

    __shared__ int   rows_s[NPAD];
    __shared__ float logits[NPAD];

    if (tid < NPAD) {
        const int* nrow = negidx + (size_t)b * NK;
        rows_s[tid] = (tid == 0 || tid > NK) ? b : nrow[tid - 1];
    }
    const float4* u4 = (const float4*)user + (size_t)b * ND4;
    float4 u0 = u4[lane];
    float4 u1 = u4[64 + lane];
    float4 u2 = u4[128 + lane];
    __syncthreads();

    const float4* it4 = (const float4*)items;
    #pragma unroll
    for (int j = 0; j < 4; ++j) {
        int ks[4];
        const float4* p[4];
        #pragma unroll
        for (int i = 0; i < 4; ++i) {
            ks[i] = wave + j * 16 + i * 4;
            p[i]  = it4 + (size_t)rows_s[ks[i]] * ND4;
        }
        float4 v0[4], v1[4], v2[4];
        #pragma unroll
        for (int i = 0; i < 4; ++i) {
            v0[i] = p[i][lane];
            v1[i] = p[i][64 + lane];
            v2[i] = p[i][128 + lane];
        }
        float acc[4];
        #pragma unroll
        for (int i = 0; i < 4; ++i) {
            float a;
            a  = u0.x * v0[i].x + u0.y * v0[i].y + u0.z * v0[i].z + u0.w * v0[i].w;
            a += u1.x * v1[i].x + u1.y * v1[i].y + u1.z * v1[i].z + u1.w * v1[i].w;
            a += u2.x * v2[i].x + u2.y * v2[i].y + u2.z * v2[i].z + u2.w * v2[i].w;
            acc[i] = a;
        }
        #pragma unroll
        for (int off = 32; off > 0; off >>= 1) {
            #pragma unroll
            for (int i = 0; i < 4; ++i)
                acc[i] += __shfl_down(acc[i], off, 64);
        }
        if (lane == 0) {
            #pragma unroll
            for (int i = 0; i < 4; ++i)
                logits[ks[i]] = acc[i];
        }
    }
    __syncthreads();

    if (tid < 64) {
        float v = (tid < NLOGITS) ? logits[tid] : -INFINITY;
        float m = v;
        #pragma unroll
        for (int off = 32; off > 0; off >>= 1)
            m = fmaxf(m, __shfl_down(m, off, 64));
        m = __shfl(m, 0, 64);
        float e = (tid < NLOGITS) ? __expf(v - m) : 0.0f;
        #pragma unroll
        for (int off = 32; off > 0; off >>= 1)
            e += __shfl_down(e, off, 64);
        if (tid == 0) {
            float loss = m + __logf(e) - logits[0];
            atomicAdd(out, loss * (1.0f / (float)NB));
        }
    }
}

extern "C" void kernel_launch(void* const* d_in, const int* in_sizes, int n_in,
                              void* d_out, int out_size, void* d_ws, size_t ws_size,
                              hipStream_t stream) {
    const float* user  = (const float*)d_in[0];   // (B, D) fp32
    const float* items = (const float*)d_in[1];   // (B, D) fp32
    const int*   negi  = (const int*)d_in[2];     // (B, K) int32
    float* out = (float*)d_out;                   // scalar fp32

    hipMemsetAsync(out, 0, sizeof(float), stream);

    if (ws_size >= WS_NEED) {
        char* ws = (char*)d_ws;
        float*        logits = (float*)(ws + WS_LOGITS_OFF);
        unsigned int* itemsh = (unsigned int*)(ws + WS_ITEMS_OFF);

        // 786432 float4 -> 3072 blocks of 256
        convert_items_f16<<<(NB * ND / 4) / 256, 256, 0, stream>>>(
            (const f4v*)items, (uint2*)itemsh);
        // 4096 rows x 8 waves = 32768 waves = 8192 blocks of 4 waves
        gather_dots_lds<<<NB * 8 / 4, 256, 0, stream>>>(
            user, itemsh, negi, logits);
        // 16 blocks x 256 threads; thread = row
        lse_reduce<<<NB / 256, 256, 0, stream>>>(logits, out);
    } else {
        u2i_loss_f32<<<NB, 256, 0, stream>>>(user, items, negi, out);
    }
}

// Round 7
// 103.585 us; speedup vs baseline: 6.7463x; 1.0937x over previous
//
#include <hip/hip_runtime.h>
#include <hip/hip_fp16.h>
#include <math.h>

// B=4096, D=768, K=60. Output: scalar fp32 mean CE loss, label 0.
// loss_b = logsumexp(logits_b) - logits_b[0].
//
// Ledger: R0 103.4 (4-disp, reg-gather) / R2 104.7 (L2 plane split: NULL)
// / R3 134.8 (fused, 4096 same-addr atomics = 62us queue, measured) /
// R4 106.5 (sched_barrier: null) / R5 698.8 (coop: latency-starved) /
// R6 113.3 (LDS-DMA gather: -7us vs reg gather).
// Conclusion: gather (~36us) is at its random-access service-rate floor
// (~384 MB of 1.5KB gathers at ~10-11 TB/s blended L2/L3); locality,
// reg-MLP and DMA-MLP all moved it <20%. Remaining controllables are
// dispatch gaps + small kernels -> consolidate to 3 dispatches:
//
//   1. convert_all_f16: items AND user fp32 -> fp16 tables; block 0
//      zeroes the 64 padded loss-accumulator slots (no memset dispatch).
//   2. gather_lse_fused: one 512-thr block per row (R3's passed body):
//      8 waves x 8 logits, fold8, LDS, wave-0 LSE -> ONE atomicAdd to
//      slot[(b&63)*16] (line-padded: 64 adds/line spread over kernel
//      lifetime -> no atomic queue, unlike R3's single address).
//   3. finish: 1 block sums 64 slots -> out.
//
// fp16 user table: identical numerics to before (user was packed to fp16
// in-register anyway), halves user-side gather traffic.

#define NB 4096
#define ND 768
#define NK 60
#define ND4  (ND / 4)          // 192 float4 per fp32 row
#define NDU  (ND / 2)          // 384 uints per fp16 row
#define NLOGITS (NK + 1)       // 61
#define NPAD 64

#define NSLOT 64               // loss accumulator slots, one 64B line each

#define WS_ITEMS_OFF 0
#define WS_USER_OFF  ((size_t)NB * ND * 2)                  // +6.29 MB
#define WS_SLOTS_OFF (WS_USER_OFF + (size_t)NB * ND * 2)    // +6.29 MB
#define WS_NEED      (WS_SLOTS_OFF + (size_t)NSLOT * 16 * 4)

typedef _Float16 h2 __attribute__((ext_vector_type(2)));
typedef float    f2 __attribute__((ext_vector_type(2)));
typedef float    f4v __attribute__((ext_vector_type(4)));

__device__ __forceinline__ float dot2_acc(unsigned int u, unsigned int v, float c) {
#if __has_builtin(__builtin_amdgcn_fdot2)
    return __builtin_amdgcn_fdot2(__builtin_bit_cast(h2, u),
                                  __builtin_bit_cast(h2, v), c, false);
#else
    f2 a = __builtin_convertvector(__builtin_bit_cast(h2, u), f2);
    f2 b = __builtin_convertvector(__builtin_bit_cast(h2, v), f2);
    return c + a.x * b.x + a.y * b.y;
#endif
}

__device__ __forceinline__ unsigned int pack_h2(float x, float y) {
    h2 h = { (_Float16)x, (_Float16)y };
    return __builtin_bit_cast(unsigned int, h);
}

// Butterfly fold: 8 per-lane partials -> every lane holds the full 64-lane
// sum of logit (lane & 7).  (Verified: absmax 0 in rounds 0/2/3/4/5/6.)
__device__ __forceinline__ float fold8(const float acc[8], int lane) {
    const int bit0 = lane & 1;
    float n[4];
    #pragma unroll
    for (int j = 0; j < 4; ++j) {
        float mine  = bit0 ? acc[2*j+1] : acc[2*j];
        float other = bit0 ? acc[2*j]   : acc[2*j+1];
        n[j] = mine + __shfl_xor(other, 1, 64);
    }
    const int bit1 = (lane >> 1) & 1;
    float s[2];
    #pragma unroll
    for (int j = 0; j < 2; ++j) {
        float mine  = bit1 ? n[2*j+1] : n[2*j];
        float other = bit1 ? n[2*j]   : n[2*j+1];
        s[j] = mine + __shfl_xor(other, 2, 64);
    }
    const int bit2 = (lane >> 2) & 1;
    float mine  = bit2 ? s[1] : s[0];
    float other = bit2 ? s[0] : s[1];
    float r = mine + __shfl_xor(other, 4, 64);
    r += __shfl_xor(r, 8, 64);
    r += __shfl_xor(r, 16, 64);
    r += __shfl_xor(r, 32, 64);
    return r;
}

// ---- phase 1: items + user fp32 -> fp16; zero the slot accumulators ----
__global__ __launch_bounds__(256) void convert_all_f16(
    const f4v* __restrict__ items,
    const f4v* __restrict__ user,
    uint2* __restrict__ itemsh,
    uint2* __restrict__ userh,
    float* __restrict__ slots)
{
    const int half = NB * ND4;                  // 786432 float4 per table
    int i = blockIdx.x * 256 + threadIdx.x;

    if (blockIdx.x == 0) {
        // zero 64 padded slots (64 x 16 floats = 1024 floats)
        ((float4*)slots)[threadIdx.x] = make_float4(0.f, 0.f, 0.f, 0.f);
    }

    const f4v* src = (i < half) ? items : user;
    uint2*     dst = (i < half) ? itemsh : userh;
    int        j   = (i < half) ? i : i - half;

    f4v v = __builtin_nontemporal_load(src + j);
    uint2 rv;
    rv.x = pack_h2(v.x, v.y);
    rv.y = pack_h2(v.z, v.w);
    dst[j] = rv;
}

// ---- phase 2: one block (8 waves) per row; gather + LSE + slot atomic ----
__global__ __launch_bounds__(512) void gather_lse_fused(
    const unsigned int* __restrict__ userh,
    const unsigned int* __restrict__ itemsh,
    const int* __restrict__ negidx,
    float* __restrict__ slots)
{
    const int tid  = threadIdx.x;
    const int lane = tid & 63;
    const int slot = tid >> 6;          // wave id, 0..7
    const int b    = blockIdx.x;

    // 8 row indices for this wave (wave-uniform -> scalar loads)
    const int* nrow = negidx + (size_t)b * NK;
    int rows[8];
    #pragma unroll
    for (int i = 0; i < 8; ++i) {
        int k = slot * 8 + i;
        rows[i] = (k == 0 || k > NK) ? b : nrow[k - 1];
    }

    // user row fp16 (same layout as item rows); L1-shared across 8 waves
    const unsigned int* ur = userh + (size_t)b * NDU;
    uint4 ua = ((const uint4*)ur)[lane];          // elements 8l..8l+7
    uint2 ub = ((const uint2*)(ur + 256))[lane];  // elements 512+4l..+3

    // 16 gather loads (proven R0/R3 inner loop)
    uint4 va[8];
    uint2 vb[8];
    #pragma unroll
    for (int i = 0; i < 8; ++i) {
        const unsigned int* ir = itemsh + (size_t)rows[i] * NDU;
        va[i] = ((const uint4*)ir)[lane];
        vb[i] = ((const uint2*)(ir + 256))[lane];
    }

    float acc[8];
    #pragma unroll
    for (int i = 0; i < 8; ++i) {
        float a = 0.0f;
        a = dot2_acc(ua.x, va[i].x, a);
        a = dot2_acc(ua.y, va[i].y, a);
        a = dot2_acc(ua.z, va[i].z, a);
        a = dot2_acc(ua.w, va[i].w, a);
        a = dot2_acc(ub.x, vb[i].x, a);
        a = dot2_acc(ub.y, vb[i].y, a);
        acc[i] = a;
    }

    float r = fold8(acc, lane);

    __shared__ float lg[NPAD];
    if (lane < 8)
        lg[slot * 8 + lane] = r;
    __syncthreads();

    // wave 0: logsumexp over 61 logits -> one line-padded atomic per block
    if (tid < 64) {
        float v  = (tid < NLOGITS) ? lg[tid] : -INFINITY;
        float p0 = lg[0];
        float m = v;
        #pragma unroll
        for (int off = 32; off > 0; off >>= 1)
            m = fmaxf(m, __shfl_down(m, off, 64));
        m = __shfl(m, 0, 64);
        float e = (tid < NLOGITS) ? __expf(v - m) : 0.0f;
        #pragma unroll
        for (int off = 32; off > 0; off >>= 1)
            e += __shfl_down(e, off, 64);
        if (tid == 0) {
            float loss = m + __logf(e) - p0;
            // 64 distinct 64B lines; ~64 adds/line spread over the whole
            // kernel -> no queue (R3's 4096-on-one-address was 62us).
            atomicAdd(&slots[(b & (NSLOT - 1)) * 16], loss);
        }
    }
}

// ---- phase 3: one tiny block: 64 slots -> mean ----
__global__ __launch_bounds__(64) void finish(
    const float* __restrict__ slots, float* __restrict__ out)
{
    const int tid = threadIdx.x;
    float s = slots[tid * 16];
    #pragma unroll
    for (int off = 32; off > 0; off >>= 1)
        s += __shfl_down(s, off, 64);
    if (tid == 0)
        out[0] = s * (1.0f / (float)NB);
}

// ---- fallback (fp32 single-kernel path) if ws too small ----
__global__ __launch_bounds__(256) void u2i_loss_f32(
    const float* __restrict__ user,
    const float* __restrict__ items,
    const int* __restrict__ negidx,
    float* __restrict__ out)
{
    const int b    = blockIdx.x;
    const int tid  = threadIdx.x;
    const int wave = tid >> 6;
    const int lane = tid & 63;

    __shared__ int   rows_s[NPAD];
    __shared__ float logits[NPAD];

    if (tid < NPAD) {
        const int* nrow = negidx + (size_t)b * NK;
        rows_s[tid] = (tid == 0 || tid > NK) ? b : nrow[tid - 1];
    }
    const float4* u4 = (const float4*)user + (size_t)b * ND4;
    float4 u0 = u4[lane];
    float4 u1 = u4[64 + lane];
    float4 u2 = u4[128 + lane];
    __syncthreads();

    const float4* it4 = (const float4*)items;
    #pragma unroll
    for (int j = 0; j < 4; ++j) {
        int ks[4];
        const float4* p[4];
        #pragma unroll
        for (int i = 0; i < 4; ++i) {
            ks[i] = wave + j * 16 + i * 4;
            p[i]  = it4 + (size_t)rows_s[ks[i]] * ND4;
        }
        float4 v0[4], v1[4], v2[4];
        #pragma unroll
        for (int i = 0; i < 4; ++i) {
            v0[i] = p[i][lane];
            v1[i] = p[i][64 + lane];
            v2[i] = p[i][128 + lane];
        }
        float acc[4];
        #pragma unroll
        for (int i = 0; i < 4; ++i) {
            float a;
            a  = u0.x * v0[i].x + u0.y * v0[i].y + u0.z * v0[i].z + u0.w * v0[i].w;
            a += u1.x * v1[i].x + u1.y * v1[i].y + u1.z * v1[i].z + u1.w * v1[i].w;
            a += u2.x * v2[i].x + u2.y * v2[i].y + u2.z * v2[i].z + u2.w * v2[i].w;
            acc[i] = a;
        }
        #pragma unroll
        for (int off = 32; off > 0; off >>= 1) {
            #pragma unroll
            for (int i = 0; i < 4; ++i)
                acc[i] += __shfl_down(acc[i], off, 64);
        }
        if (lane == 0) {
            #pragma unroll
            for (int i = 0; i < 4; ++i)
                logits[ks[i]] = acc[i];
        }
    }
    __syncthreads();

    if (tid < 64) {
        float v = (tid < NLOGITS) ? logits[tid] : -INFINITY;
        float m = v;
        #pragma unroll
        for (int off = 32; off > 0; off >>= 1)
            m = fmaxf(m, __shfl_down(m, off, 64));
        m = __shfl(m, 0, 64);
        float e = (tid < NLOGITS) ? __expf(v - m) : 0.0f;
        #pragma unroll
        for (int off = 32; off > 0; off >>= 1)
            e += __shfl_down(e, off, 64);
        if (tid == 0) {
            float loss = m + __logf(e) - logits[0];
            atomicAdd(out, loss * (1.0f / (float)NB));
        }
    }
}

extern "C" void kernel_launch(void* const* d_in, const int* in_sizes, int n_in,
                              void* d_out, int out_size, void* d_ws, size_t ws_size,
                              hipStream_t stream) {
    const float* user  = (const float*)d_in[0];   // (B, D) fp32
    const float* items = (const float*)d_in[1];   // (B, D) fp32
    const int*   negi  = (const int*)d_in[2];     // (B, K) int32
    float* out = (float*)d_out;                   // scalar fp32

    if (ws_size >= WS_NEED) {
        char* ws = (char*)d_ws;
        unsigned int* itemsh = (unsigned int*)(ws + WS_ITEMS_OFF);
        unsigned int* userh  = (unsigned int*)(ws + WS_USER_OFF);
        float*        slots  = (float*)(ws + WS_SLOTS_OFF);

        // 2 x 786432 float4 -> 6144 blocks of 256
        convert_all_f16<<<2 * (NB * ND / 4) / 256, 256, 0, stream>>>(
            (const f4v*)items, (const f4v*)user,
            (uint2*)itemsh, (uint2*)userh, slots);
        // one 8-wave block per row; gather + LSE + padded-slot atomic
        gather_lse_fused<<<NB, 512, 0, stream>>>(
            userh, itemsh, negi, slots);
        finish<<<1, 64, 0, stream>>>(slots, out);
    } else {
        hipMemsetAsync(out, 0, sizeof(float), stream);
        u2i_loss_f32<<<NB, 256, 0, stream>>>(user, items, negi, out);
    }
}